// Round 14
// baseline (356.154 us; speedup 1.0000x reference)
//
#include <hip/hip_runtime.h>
#include <hip/hip_bf16.h>

#define BB 4
#define NN 2048
#define DD 1024
#define HH 16

using bf16 = __hip_bfloat16;
typedef __attribute__((ext_vector_type(8))) short bf16x8s;
typedef __attribute__((ext_vector_type(4))) float f32x4;

#define GLOAD_LDS16(gp, lp)                                                   \
  __builtin_amdgcn_global_load_lds(                                           \
      (const __attribute__((address_space(1))) void*)(gp),                    \
      (__attribute__((address_space(3))) void*)(lp), 16, 0, 0)

// ---------------- cast f32 -> bf16 (vectorized x4) ----------------
__global__ void cast_f32_bf16(const float* __restrict__ in, bf16* __restrict__ out, int n) {
  int i = (blockIdx.x * blockDim.x + threadIdx.x) * 4;
  if (i >= n) return;
  float4 v = *reinterpret_cast<const float4*>(in + i);
  ushort4 o;
  bf16 t0 = __float2bfloat16(v.x); o.x = *reinterpret_cast<unsigned short*>(&t0);
  bf16 t1 = __float2bfloat16(v.y); o.y = *reinterpret_cast<unsigned short*>(&t1);
  bf16 t2 = __float2bfloat16(v.z); o.z = *reinterpret_cast<unsigned short*>(&t2);
  bf16 t3 = __float2bfloat16(v.w); o.w = *reinterpret_cast<unsigned short*>(&t3);
  *reinterpret_cast<ushort4*>(out + i) = o;
}

// ---------------- transpose + cast: in[R,C] f32 -> out[C,R] bf16 ----------------
__device__ __forceinline__ void transpose_tile(const float* __restrict__ in,
                                               bf16* __restrict__ out, int R, int C) {
  __shared__ float t[32][33];
  int c0 = blockIdx.x * 32, r0 = blockIdx.y * 32;
  int tx = threadIdx.x, ty = threadIdx.y;  // block (32,8)
#pragma unroll
  for (int i = 0; i < 4; i++)
    t[ty + i * 8][tx] = in[(size_t)(r0 + ty + i * 8) * C + c0 + tx];
  __syncthreads();
#pragma unroll
  for (int i = 0; i < 4; i++)
    out[(size_t)(c0 + ty + i * 8) * R + r0 + tx] = __float2bfloat16(t[tx][ty + i * 8]);
}

// fused: the four 1024x1024 weight transposes in one launch (z selects matrix)
__global__ void transpose_cast4(const float* __restrict__ W0, const float* __restrict__ W1,
                                const float* __restrict__ W2, const float* __restrict__ W3,
                                bf16* __restrict__ O0, bf16* __restrict__ O1,
                                bf16* __restrict__ O2, bf16* __restrict__ O3) {
  const float* in; bf16* out;
  switch (blockIdx.z) {
    case 0: in = W0; out = O0; break;
    case 1: in = W1; out = O1; break;
    case 2: in = W2; out = O2; break;
    default: in = W3; out = O3; break;
  }
  transpose_tile(in, out, DD, DD);
}

// fused: the two 2048x1024 Wc/We transposes in one launch
__global__ void transpose_cast2(const float* __restrict__ W0, const float* __restrict__ W1,
                                bf16* __restrict__ O0, bf16* __restrict__ O1) {
  const float* in = blockIdx.z ? W1 : W0;
  bf16* out = blockIdx.z ? O1 : O0;
  transpose_tile(in, out, NN, DD);
}

// fused cg prep: one read of cg -> cgb (cast, same layout) AND cgT (cast, transposed)
__global__ void cg_prep(const float* __restrict__ in, bf16* __restrict__ outN,
                        bf16* __restrict__ outT) {
  __shared__ float t[32][33];
  int c0 = blockIdx.x * 32, r0 = blockIdx.y * 32;
  int tx = threadIdx.x, ty = threadIdx.y;  // block (32,8)
#pragma unroll
  for (int i = 0; i < 4; i++) {
    float v = in[(size_t)(r0 + ty + i * 8) * NN + c0 + tx];
    t[ty + i * 8][tx] = v;
    outN[(size_t)(r0 + ty + i * 8) * NN + c0 + tx] = __float2bfloat16(v);
  }
  __syncthreads();
#pragma unroll
  for (int i = 0; i < 4; i++)
    outT[(size_t)(c0 + ty + i * 8) * NN + r0 + tx] = __float2bfloat16(t[tx][ty + i * 8]);
}

// ---------------- bf16->bf16 transpose of V into per-head layout ----------------
// Vb [B*N][D] -> Vt [B*H][64][N]  (Vt[bh][d][n] = Vb[b*N+n][h*64+d])
__global__ void transpose_v(const bf16* __restrict__ Vb, bf16* __restrict__ Vt) {
  __shared__ short t[32][33];
  int bh = blockIdx.z; int b = bh >> 4, h = bh & 15;
  int n0 = blockIdx.x * 32, d0 = blockIdx.y * 32;
  int tx = threadIdx.x, ty = threadIdx.y;  // block (32,8)
#pragma unroll
  for (int i = 0; i < 4; i++)
    t[ty + i * 8][tx] = reinterpret_cast<const short*>(Vb)[
        (size_t)(b * NN + n0 + ty + i * 8) * DD + h * 64 + d0 + tx];
  __syncthreads();
#pragma unroll
  for (int i = 0; i < 4; i++)
    reinterpret_cast<short*>(Vt)[(size_t)(bh * 64 + d0 + ty + i * 8) * NN + n0 + tx] =
        t[tx][ty + i * 8];
}

// ---------------- GEMM tile body (compile-time rowadd) ----------------
template <int OUT_BF16, int HAS_ROWADD>
__device__ __forceinline__ void gemm_tile(
    const bf16* __restrict__ A, const bf16* __restrict__ BT, void* __restrict__ Cout,
    const float* __restrict__ bias, const float* __restrict__ rowadd,
    int Nc, int K, float scale, int brow, int bcol, short* As, short* Bs) {
  const int tid = threadIdx.x;
  const int l = tid & 63, w = tid >> 6;
  const int wr = (w >> 1) * 64, wc = (w & 1) * 64;
  const int lr = l & 15, lg = l >> 4;
  const int swz = lr & 7;
  f32x4 acc[4][4] = {};
  for (int k0 = 0; k0 < K; k0 += 64) {
#pragma unroll
    for (int i = 0; i < 4; i++) {
      int c = i * 256 + tid;          // chunk index 0..1023 (16B chunks)
      int row = c >> 3, gch = (c & 7) ^ (row & 7);
      short* lA = As + (size_t)(i * 256 + w * 64) * 8;  // wave-uniform dest
      GLOAD_LDS16(A + (size_t)(brow + row) * K + k0 + gch * 8, lA);
      short* lB = Bs + (size_t)(i * 256 + w * 64) * 8;
      GLOAD_LDS16(BT + (size_t)(bcol + row) * K + k0 + gch * 8, lB);
    }
    __syncthreads();
#pragma unroll
    for (int t = 0; t < 2; t++) {
      bf16x8s a[4], bfr[4];
#pragma unroll
      for (int m = 0; m < 4; m++)
        a[m] = *reinterpret_cast<const bf16x8s*>(
            &As[(wr + m * 16 + lr) * 64 + ((t * 4 + lg) ^ swz) * 8]);
#pragma unroll
      for (int n = 0; n < 4; n++)
        bfr[n] = *reinterpret_cast<const bf16x8s*>(
            &Bs[(wc + n * 16 + lr) * 64 + ((t * 4 + lg) ^ swz) * 8]);
#pragma unroll
      for (int m = 0; m < 4; m++)
#pragma unroll
        for (int n = 0; n < 4; n++)
          acc[m][n] = __builtin_amdgcn_mfma_f32_16x16x32_bf16(a[m], bfr[n], acc[m][n], 0, 0, 0);
    }
    __syncthreads();
  }
#pragma unroll
  for (int m = 0; m < 4; m++) {
#pragma unroll
    for (int n = 0; n < 4; n++) {
      int col = bcol + wc + n * 16 + lr;
      float bv = bias[col];
#pragma unroll
      for (int r = 0; r < 4; r++) {
        int row = brow + wr + m * 16 + lg * 4 + r;
        float v = acc[m][n][r] + bv;
        if (HAS_ROWADD) v += rowadd[(size_t)(row & (NN - 1)) * Nc + col];
        v *= scale;
        if (OUT_BF16)
          reinterpret_cast<bf16*>(Cout)[(size_t)row * Nc + col] = __float2bfloat16(v);
        else
          reinterpret_cast<float*>(Cout)[(size_t)row * Nc + col] = v;
      }
    }
  }
}

// ---------------- bf16 MFMA GEMM, 128x128 tile, BK=64, XCD-swizzled ----------------
template <int OUT_BF16, int HAS_ROWADD>
__global__ __launch_bounds__(256) void gemm_bt(
    const bf16* __restrict__ A, const bf16* __restrict__ BT, void* __restrict__ Cout,
    const float* __restrict__ bias, const float* __restrict__ rowadd,
    int M, int Nc, int K, float scale) {
  __shared__ short As[128 * 64];
  __shared__ short Bs[128 * 64];
  const int nbx = gridDim.x;
  const int nwg = nbx * gridDim.y;
  const int wg = blockIdx.y * nbx + blockIdx.x;
  const int swg = (wg & 7) * (nwg >> 3) + (wg >> 3);
  const int bxi = swg % nbx, byi = swg / nbx;
  gemm_tile<OUT_BF16, HAS_ROWADD>(A, BT, Cout, bias, rowadd, Nc, K, scale,
                                  byi * 128, bxi * 128, As, Bs);
}

// ---------------- dual GEMM: the two 2048x1024x2048 cg GEMMs fill the chip ----------
__global__ __launch_bounds__(256) void gemm_dual(
    const bf16* __restrict__ A0, const bf16* __restrict__ B0, float* __restrict__ C0,
    const float* __restrict__ bias0,
    const bf16* __restrict__ A1, const bf16* __restrict__ B1, float* __restrict__ C1,
    const float* __restrict__ bias1, int Nc, int K) {
  __shared__ short As[128 * 64];
  __shared__ short Bs[128 * 64];
  const int nbx = gridDim.x;
  const int nwg = nbx * gridDim.y;
  const int wg = blockIdx.y * nbx + blockIdx.x;
  const int swg = (wg & 7) * (nwg >> 3) + (wg >> 3);
  const int bxi = swg % nbx, byi = swg / nbx;
  if (blockIdx.z == 0)
    gemm_tile<0, 0>(A0, B0, C0, bias0, nullptr, Nc, K, 1.0f, byi * 128, bxi * 128, As, Bs);
  else
    gemm_tile<0, 0>(A1, B1, C1, bias1, nullptr, Nc, K, 1.0f, byi * 128, bxi * 128, As, Bs);
}

// ---------------- flash attention: 256-row q-tile, 8 waves x 32 q-rows each ----
// Each wave runs TWO 16-row groups (A: q=lr, B: q=16+lr) off ONE K/V staging+
// barrier pair: staging traffic, barriers, and mask/addr overhead per q-row halve
// vs R10, while total MFMA/VALU per CU stays constant. K ds_reads re-issued for
// group B (8 cheap b128) to stagger register pressure; V reads shared by both PV
// groups. grid 512 = exactly 2 blocks/CU (LDS 52KB). Swapped-operand mfma(K,Q):
// q = lane&15, kv on reg axis -> in-lane softmax, scalar m/l per group.
__global__ __launch_bounds__(512, 2) void attn_k(
    const bf16* __restrict__ Qb, const bf16* __restrict__ Kb, const bf16* __restrict__ Vt,
    const float* __restrict__ mask, bf16* __restrict__ Ob) {
  constexpr int PPAD = 72;
  __shared__ short Ks[64 * 64];
  __shared__ short Vts[64 * 64];
  __shared__ short Ps[8][32 * PPAD];   // 8 waves x 32 q-rows
  const int tid = threadIdx.x;
  // XCD swizzle: x = xcd, i = intra-chunk (64/XCD); h fastest, then q-tile
  const int wg = blockIdx.x;
  const int x = wg & 7, i = wg >> 3;
  const int b = x >> 1;
  const int h = ((x & 1) << 3) | (i & 7);
  const int q0 = ((i >> 3) & 7) * 256;
  const int l = tid & 63, w = tid >> 6;   // 8 waves
  const int lr = l & 15, lg = l >> 4, lk = lg * 8;
  const int swz = lr & 7;

  // Q fragments for the two groups (rows q0+w*32+lr and +16)
  const size_t qoffA = (size_t)(b * NN + q0 + w * 32 + lr) * DD + h * 64;
  const size_t qoffB = qoffA + (size_t)16 * DD;
  bf16x8s qf0a = *reinterpret_cast<const bf16x8s*>(Qb + qoffA + lk);
  bf16x8s qf1a = *reinterpret_cast<const bf16x8s*>(Qb + qoffA + 32 + lk);
  bf16x8s qf0b = *reinterpret_cast<const bf16x8s*>(Qb + qoffB + lk);
  bf16x8s qf1b = *reinterpret_cast<const bf16x8s*>(Qb + qoffB + 32 + lk);

  f32x4 accA[4] = {}, accB[4] = {};
  float mrunA = -1e30f, lrunA = 0.f;
  float mrunB = -1e30f, lrunB = 0.f;

  const size_t kbase = (size_t)b * NN * DD + h * 64;
  const size_t vbase = (size_t)(b * HH + h) * 64 * NN;
  const float* mptrA = mask + (size_t)(q0 + w * 32 + lr) * NN + lg * 4;
  const float* mptrB = mptrA + (size_t)16 * NN;

  // staging: 512 threads cover the 512 16B chunks of each tile (1 K + 1 V chunk each)
  const int r0 = tid >> 3, ch0 = tid & 7;
  const bf16* kg0 = Kb + kbase + (size_t)r0 * DD + ch0 * 8;
  const bf16* vg0 = Vt + vbase + (size_t)r0 * NN + ch0 * 8;
  // LDS dest slot ch0^(row&7) holds global chunk ch0 (read side XORs the same)
  short* kw0 = &Ks[r0 * 64 + (ch0 ^ (r0 & 7)) * 8];
  short* vw0 = &Vts[r0 * 64 + (ch0 ^ (r0 & 7)) * 8];

  uint4 kr0, vr0;
  kr0 = *reinterpret_cast<const uint4*>(kg0);   // prologue: prefetch tile 0
  vr0 = *reinterpret_cast<const uint4*>(vg0);

  short* Pw = &Ps[w][0];

  for (int jt = 0; jt < NN; jt += 64) {
    __syncthreads();  // prior tile's readers done before overwrite
    *reinterpret_cast<uint4*>(kw0) = kr0;
    *reinterpret_cast<uint4*>(vw0) = vr0;
    // group A mask loads, issued early (vmcnt drain for these won't flush prefetch)
    float4 ma0 = *reinterpret_cast<const float4*>(mptrA + jt + 0);
    float4 ma1 = *reinterpret_cast<const float4*>(mptrA + jt + 16);
    float4 ma2 = *reinterpret_cast<const float4*>(mptrA + jt + 32);
    float4 ma3 = *reinterpret_cast<const float4*>(mptrA + jt + 48);
    if (jt + 64 < NN) {  // prefetch next tile; loads fly during compute below
      kr0 = *reinterpret_cast<const uint4*>(kg0 + (size_t)(jt + 64) * DD);
      vr0 = *reinterpret_cast<const uint4*>(vg0 + jt + 64);
    }
    __syncthreads();

    // ---- group A: S^T = K Q^T  (s[jj][r] = S[kv = jt+jj*16+lg*4+r][q=lr]) ----
    f32x4 s[4];
#pragma unroll
    for (int jj = 0; jj < 4; jj++) {
      bf16x8s k0 = *reinterpret_cast<const bf16x8s*>(
          &Ks[(jj * 16 + lr) * 64 + ((0 + lg) ^ swz) * 8]);
      bf16x8s k1 = *reinterpret_cast<const bf16x8s*>(
          &Ks[(jj * 16 + lr) * 64 + ((4 + lg) ^ swz) * 8]);
      f32x4 z = {0.f, 0.f, 0.f, 0.f};
      z = __builtin_amdgcn_mfma_f32_16x16x32_bf16(k0, qf0a, z, 0, 0, 0);
      s[jj] = __builtin_amdgcn_mfma_f32_16x16x32_bf16(k1, qf1a, z, 0, 0, 0);
    }
    // group B mask loads: issued now, consumed after softmax A (latency covered)
    float4 mb0 = *reinterpret_cast<const float4*>(mptrB + jt + 0);
    float4 mb1 = *reinterpret_cast<const float4*>(mptrB + jt + 16);
    float4 mb2 = *reinterpret_cast<const float4*>(mptrB + jt + 32);
    float4 mb3 = *reinterpret_cast<const float4*>(mptrB + jt + 48);

    // logits A (log2 domain; log2e folded into Q)
    float lv[4][4];
    lv[0][0] = s[0][0] * ma0.x; lv[0][1] = s[0][1] * ma0.y;
    lv[0][2] = s[0][2] * ma0.z; lv[0][3] = s[0][3] * ma0.w;
    lv[1][0] = s[1][0] * ma1.x; lv[1][1] = s[1][1] * ma1.y;
    lv[1][2] = s[1][2] * ma1.z; lv[1][3] = s[1][3] * ma1.w;
    lv[2][0] = s[2][0] * ma2.x; lv[2][1] = s[2][1] * ma2.y;
    lv[2][2] = s[2][2] * ma2.z; lv[2][3] = s[2][3] * ma2.w;
    lv[3][0] = s[3][0] * ma3.x; lv[3][1] = s[3][1] * ma3.y;
    lv[3][2] = s[3][2] * ma3.z; lv[3][3] = s[3][3] * ma3.w;
    {
      float mx0 = fmaxf(fmaxf(lv[0][0], lv[0][1]), fmaxf(lv[0][2], lv[0][3]));
      float mx1 = fmaxf(fmaxf(lv[1][0], lv[1][1]), fmaxf(lv[1][2], lv[1][3]));
      float mx2 = fmaxf(fmaxf(lv[2][0], lv[2][1]), fmaxf(lv[2][2], lv[2][3]));
      float mx3 = fmaxf(fmaxf(lv[3][0], lv[3][1]), fmaxf(lv[3][2], lv[3][3]));
      float mx = fmaxf(fmaxf(mx0, mx1), fmaxf(mx2, mx3));
      mx = fmaxf(mx, __shfl_xor(mx, 16, 64));
      mx = fmaxf(mx, __shfl_xor(mx, 32, 64));
      if (__any(mx > mrunA + 11.0f)) {
        float mnew = fmaxf(mrunA, mx);
        float sc = __builtin_amdgcn_exp2f(mrunA - mnew);
        mrunA = mnew;
        lrunA *= sc;
#pragma unroll
        for (int s4 = 0; s4 < 4; s4++)
#pragma unroll
          for (int r = 0; r < 4; r++) accA[s4][r] *= sc;
      }
      float rs = 0.f;
#pragma unroll
      for (int jj = 0; jj < 4; jj++) {
        float p0 = __builtin_amdgcn_exp2f(lv[jj][0] - mrunA);
        float p1 = __builtin_amdgcn_exp2f(lv[jj][1] - mrunA);
        float p2 = __builtin_amdgcn_exp2f(lv[jj][2] - mrunA);
        float p3 = __builtin_amdgcn_exp2f(lv[jj][3] - mrunA);
        rs += (p0 + p1) + (p2 + p3);
        ushort4 pk;
        bf16 c0 = __float2bfloat16(p0); pk.x = *reinterpret_cast<unsigned short*>(&c0);
        bf16 c1 = __float2bfloat16(p1); pk.y = *reinterpret_cast<unsigned short*>(&c1);
        bf16 c2 = __float2bfloat16(p2); pk.z = *reinterpret_cast<unsigned short*>(&c2);
        bf16 c3 = __float2bfloat16(p3); pk.w = *reinterpret_cast<unsigned short*>(&c3);
        *reinterpret_cast<ushort4*>(&Pw[lr * PPAD + jj * 16 + lg * 4]) = pk;
      }
      rs += __shfl_xor(rs, 16, 64);
      rs += __shfl_xor(rs, 32, 64);
      lrunA += rs;
    }

    // ---- group B: S^T = K Q^T (K re-read: 8 cheap b128, staggers reg pressure) ----
#pragma unroll
    for (int jj = 0; jj < 4; jj++) {
      bf16x8s k0 = *reinterpret_cast<const bf16x8s*>(
          &Ks[(jj * 16 + lr) * 64 + ((0 + lg) ^ swz) * 8]);
      bf16x8s k1 = *reinterpret_cast<const bf16x8s*>(
          &Ks[(jj * 16 + lr) * 64 + ((4 + lg) ^ swz) * 8]);
      f32x4 z = {0.f, 0.f, 0.f, 0.f};
      z = __builtin_amdgcn_mfma_f32_16x16x32_bf16(k0, qf0b, z, 0, 0, 0);
      s[jj] = __builtin_amdgcn_mfma_f32_16x16x32_bf16(k1, qf1b, z, 0, 0, 0);
    }
    lv[0][0] = s[0][0] * mb0.x; lv[0][1] = s[0][1] * mb0.y;
    lv[0][2] = s[0][2] * mb0.z; lv[0][3] = s[0][3] * mb0.w;
    lv[1][0] = s[1][0] * mb1.x; lv[1][1] = s[1][1] * mb1.y;
    lv[1][2] = s[1][2] * mb1.z; lv[1][3] = s[1][3] * mb1.w;
    lv[2][0] = s[2][0] * mb2.x; lv[2][1] = s[2][1] * mb2.y;
    lv[2][2] = s[2][2] * mb2.z; lv[2][3] = s[2][3] * mb2.w;
    lv[3][0] = s[3][0] * mb3.x; lv[3][1] = s[3][1] * mb3.y;
    lv[3][2] = s[3][2] * mb3.z; lv[3][3] = s[3][3] * mb3.w;
    {
      float mx0 = fmaxf(fmaxf(lv[0][0], lv[0][1]), fmaxf(lv[0][2], lv[0][3]));
      float mx1 = fmaxf(fmaxf(lv[1][0], lv[1][1]), fmaxf(lv[1][2], lv[1][3]));
      float mx2 = fmaxf(fmaxf(lv[2][0], lv[2][1]), fmaxf(lv[2][2], lv[2][3]));
      float mx3 = fmaxf(fmaxf(lv[3][0], lv[3][1]), fmaxf(lv[3][2], lv[3][3]));
      float mx = fmaxf(fmaxf(mx0, mx1), fmaxf(mx2, mx3));
      mx = fmaxf(mx, __shfl_xor(mx, 16, 64));
      mx = fmaxf(mx, __shfl_xor(mx, 32, 64));
      if (__any(mx > mrunB + 11.0f)) {
        float mnew = fmaxf(mrunB, mx);
        float sc = __builtin_amdgcn_exp2f(mrunB - mnew);
        mrunB = mnew;
        lrunB *= sc;
#pragma unroll
        for (int s4 = 0; s4 < 4; s4++)
#pragma unroll
          for (int r = 0; r < 4; r++) accB[s4][r] *= sc;
      }
      float rs = 0.f;
#pragma unroll
      for (int jj = 0; jj < 4; jj++) {
        float p0 = __builtin_amdgcn_exp2f(lv[jj][0] - mrunB);
        float p1 = __builtin_amdgcn_exp2f(lv[jj][1] - mrunB);
        float p2 = __builtin_amdgcn_exp2f(lv[jj][2] - mrunB);
        float p3 = __builtin_amdgcn_exp2f(lv[jj][3] - mrunB);
        rs += (p0 + p1) + (p2 + p3);
        ushort4 pk;
        bf16 c0 = __float2bfloat16(p0); pk.x = *reinterpret_cast<unsigned short*>(&c0);
        bf16 c1 = __float2bfloat16(p1); pk.y = *reinterpret_cast<unsigned short*>(&c1);
        bf16 c2 = __float2bfloat16(p2); pk.z = *reinterpret_cast<unsigned short*>(&c2);
        bf16 c3 = __float2bfloat16(p3); pk.w = *reinterpret_cast<unsigned short*>(&c3);
        *reinterpret_cast<ushort4*>(&Pw[(16 + lr) * PPAD + jj * 16 + lg * 4]) = pk;
      }
      rs += __shfl_xor(rs, 16, 64);
      rs += __shfl_xor(rs, 32, 64);
      lrunB += rs;
    }

    // wave-private P: drain DS writes, fence the scheduler, no block barrier
    asm volatile("s_waitcnt lgkmcnt(0)" ::: "memory");
    __builtin_amdgcn_sched_barrier(0);

    // O^T += V^T P^T for both groups (V reads shared)
    bf16x8s pb0a = *reinterpret_cast<const bf16x8s*>(&Pw[lr * PPAD + lk]);
    bf16x8s pb1a = *reinterpret_cast<const bf16x8s*>(&Pw[lr * PPAD + 32 + lk]);
    bf16x8s pb0b = *reinterpret_cast<const bf16x8s*>(&Pw[(16 + lr) * PPAD + lk]);
    bf16x8s pb1b = *reinterpret_cast<const bf16x8s*>(&Pw[(16 + lr) * PPAD + 32 + lk]);
#pragma unroll
    for (int s4 = 0; s4 < 4; s4++) {
      bf16x8s v0 = *reinterpret_cast<const bf16x8s*>(
          &Vts[(s4 * 16 + lr) * 64 + ((0 + lg) ^ swz) * 8]);
      bf16x8s v1 = *reinterpret_cast<const bf16x8s*>(
          &Vts[(s4 * 16 + lr) * 64 + ((4 + lg) ^ swz) * 8]);
      accA[s4] = __builtin_amdgcn_mfma_f32_16x16x32_bf16(v0, pb0a, accA[s4], 0, 0, 0);
      accA[s4] = __builtin_amdgcn_mfma_f32_16x16x32_bf16(v1, pb1a, accA[s4], 0, 0, 0);
      accB[s4] = __builtin_amdgcn_mfma_f32_16x16x32_bf16(v0, pb0b, accB[s4], 0, 0, 0);
      accB[s4] = __builtin_amdgcn_mfma_f32_16x16x32_bf16(v1, pb1b, accB[s4], 0, 0, 0);
    }
  }

  // epilogue: normalize (rcp), pack 4 consecutive d per s4 -> 8B stores, both groups
  float rlA = __builtin_amdgcn_rcpf(lrunA);
  float rlB = __builtin_amdgcn_rcpf(lrunB);
  const size_t orowA = (size_t)(b * NN + q0 + w * 32 + lr) * DD + h * 64;
  const size_t orowB = orowA + (size_t)16 * DD;
#pragma unroll
  for (int s4 = 0; s4 < 4; s4++) {
    ushort4 o;
    bf16 c0 = __float2bfloat16(accA[s4][0] * rlA); o.x = *reinterpret_cast<unsigned short*>(&c0);
    bf16 c1 = __float2bfloat16(accA[s4][1] * rlA); o.y = *reinterpret_cast<unsigned short*>(&c1);
    bf16 c2 = __float2bfloat16(accA[s4][2] * rlA); o.z = *reinterpret_cast<unsigned short*>(&c2);
    bf16 c3 = __float2bfloat16(accA[s4][3] * rlA); o.w = *reinterpret_cast<unsigned short*>(&c3);
    *reinterpret_cast<ushort4*>(reinterpret_cast<unsigned short*>(Ob) + orowA + s4 * 16 + lg * 4) = o;
    bf16 d0 = __float2bfloat16(accB[s4][0] * rlB); o.x = *reinterpret_cast<unsigned short*>(&d0);
    bf16 d1 = __float2bfloat16(accB[s4][1] * rlB); o.y = *reinterpret_cast<unsigned short*>(&d1);
    bf16 d2 = __float2bfloat16(accB[s4][2] * rlB); o.z = *reinterpret_cast<unsigned short*>(&d2);
    bf16 d3 = __float2bfloat16(accB[s4][3] * rlB); o.w = *reinterpret_cast<unsigned short*>(&d3);
    *reinterpret_cast<ushort4*>(reinterpret_cast<unsigned short*>(Ob) + orowB + s4 * 16 + lg * 4) = o;
  }
}

// ---------------- orchestration ----------------
extern "C" void kernel_launch(void* const* d_in, const int* in_sizes, int n_in,
                              void* d_out, int out_size, void* d_ws, size_t ws_size,
                              hipStream_t stream) {
  (void)in_sizes; (void)n_in; (void)out_size; (void)ws_size;
  const float* x    = (const float*)d_in[0];
  const float* cg   = (const float*)d_in[1];
  const float* mask = (const float*)d_in[2];
  const float* Wq   = (const float*)d_in[3];
  const float* bq   = (const float*)d_in[4];
  const float* Wk   = (const float*)d_in[5];
  const float* bk   = (const float*)d_in[6];
  const float* Wc   = (const float*)d_in[7];
  const float* bc   = (const float*)d_in[8];
  const float* We   = (const float*)d_in[9];
  const float* be   = (const float*)d_in[10];
  const float* Wv   = (const float*)d_in[11];
  const float* bv   = (const float*)d_in[12];
  const float* Wo   = (const float*)d_in[13];
  const float* bo   = (const float*)d_in[14];

  auto MB = [](size_t m) { return m << 20; };
  char* ws = (char*)d_ws;
  bf16* xb   = (bf16*)(ws + MB(0));    // 16 MB
  bf16* WqT  = (bf16*)(ws + MB(16));   // 2 MB each
  bf16* WkT  = (bf16*)(ws + MB(18));
  bf16* WvT  = (bf16*)(ws + MB(20));
  bf16* WoT  = (bf16*)(ws + MB(22));
  float* cq  = (float*)(ws + MB(24));  // 8 MB f32 (dead after Q GEMM)
  float* ck  = (float*)(ws + MB(32));  // 8 MB f32 (dead after K GEMM)
  bf16* Qb   = (bf16*)(ws + MB(40));   // 16 MB
  bf16* Kb   = (bf16*)(ws + MB(56));   // 16 MB
  bf16* Vb   = (bf16*)(ws + MB(72));   // 16 MB (dead after transpose_v)
  bf16* Vt   = (bf16*)(ws + MB(88));   // 16 MB -> peak 104 MB
  bf16* Ob   = (bf16*)(ws + MB(72));   // overlays Vb (dead)
  // overlays, dead after cq/ck GEMMs (before Qb/Kb are written):
  bf16* WcT  = (bf16*)(ws + MB(40));   // 4 MB
  bf16* WeT  = (bf16*)(ws + MB(44));   // 4 MB
  bf16* cgb  = (bf16*)(ws + MB(48));   // 8 MB
  bf16* cgT  = (bf16*)(ws + MB(56));   // 8 MB

  cast_f32_bf16<<<dim3(BB * NN * DD / 4 / 256), 256, 0, stream>>>(x, xb, BB * NN * DD);
  dim3 tb(32, 8);
  cg_prep<<<dim3(NN / 32, NN / 32), tb, 0, stream>>>(cg, cgb, cgT);
  transpose_cast4<<<dim3(DD / 32, DD / 32, 4), tb, 0, stream>>>(
      Wq, Wk, Wv, Wo, WqT, WkT, WvT, WoT);
  transpose_cast2<<<dim3(DD / 32, NN / 32, 2), tb, 0, stream>>>(Wc, We, WcT, WeT);

  // cq = cg@Wc + bc AND ck = cg^T@We + be in one full-chip launch (256 blocks)
  gemm_dual<<<dim3(DD / 128, NN / 128, 2), 256, 0, stream>>>(
      cgb, WcT, cq, bc, cgT, WeT, ck, be, DD, NN);
  // Q = (0.125*log2e)*(x@Wq + bq + cq[row]) ; K = x@Wk + bk + ck[row] ; V = x@Wv + bv
  gemm_bt<1, 1><<<dim3(DD / 128, BB * NN / 128), 256, 0, stream>>>(
      xb, WqT, Qb, bq, cq, BB * NN, DD, DD, 0.125f * 1.4426950408889634f);
  gemm_bt<1, 1><<<dim3(DD / 128, BB * NN / 128), 256, 0, stream>>>(
      xb, WkT, Kb, bk, ck, BB * NN, DD, DD, 1.0f);
  gemm_bt<1, 0><<<dim3(DD / 128, BB * NN / 128), 256, 0, stream>>>(
      xb, WvT, Vb, bv, nullptr, BB * NN, DD, DD, 1.0f);

  transpose_v<<<dim3(NN / 32, 2, BB * HH), tb, 0, stream>>>(Vb, Vt);

  attn_k<<<dim3(NN / 256 * HH * BB), 512, 0, stream>>>(Qb, Kb, Vt, mask, Ob);

  // out = attn@Wo + bo  (f32 out)
  gemm_bt<0, 0><<<dim3(DD / 128, BB * NN / 128), 256, 0, stream>>>(
      Ob, WoT, (float*)d_out, bo, nullptr, BB * NN, DD, DD, 1.0f);
}

// Round 15
// 311.320 us; speedup vs baseline: 1.1440x; 1.1440x over previous
//
#include <hip/hip_runtime.h>
#include <hip/hip_bf16.h>

#define BB 4
#define NN 2048
#define DD 1024
#define HH 16

using bf16 = __hip_bfloat16;
typedef __attribute__((ext_vector_type(8))) short bf16x8s;
typedef __attribute__((ext_vector_type(4))) float f32x4;

#define GLOAD_LDS16(gp, lp)                                                   \
  __builtin_amdgcn_global_load_lds(                                           \
      (const __attribute__((address_space(1))) void*)(gp),                    \
      (__attribute__((address_space(3))) void*)(lp), 16, 0, 0)

// ---------------- cast f32 -> bf16 (vectorized x4) ----------------
__global__ void cast_f32_bf16(const float* __restrict__ in, bf16* __restrict__ out, int n) {
  int i = (blockIdx.x * blockDim.x + threadIdx.x) * 4;
  if (i >= n) return;
  float4 v = *reinterpret_cast<const float4*>(in + i);
  ushort4 o;
  bf16 t0 = __float2bfloat16(v.x); o.x = *reinterpret_cast<unsigned short*>(&t0);
  bf16 t1 = __float2bfloat16(v.y); o.y = *reinterpret_cast<unsigned short*>(&t1);
  bf16 t2 = __float2bfloat16(v.z); o.z = *reinterpret_cast<unsigned short*>(&t2);
  bf16 t3 = __float2bfloat16(v.w); o.w = *reinterpret_cast<unsigned short*>(&t3);
  *reinterpret_cast<ushort4*>(out + i) = o;
}

// ---------------- transpose + cast: in[R,C] f32 -> out[C,R] bf16 ----------------
__device__ __forceinline__ void transpose_tile(const float* __restrict__ in,
                                               bf16* __restrict__ out, int R, int C) {
  __shared__ float t[32][33];
  int c0 = blockIdx.x * 32, r0 = blockIdx.y * 32;
  int tx = threadIdx.x, ty = threadIdx.y;  // block (32,8)
#pragma unroll
  for (int i = 0; i < 4; i++)
    t[ty + i * 8][tx] = in[(size_t)(r0 + ty + i * 8) * C + c0 + tx];
  __syncthreads();
#pragma unroll
  for (int i = 0; i < 4; i++)
    out[(size_t)(c0 + ty + i * 8) * R + r0 + tx] = __float2bfloat16(t[tx][ty + i * 8]);
}

// fused: the four 1024x1024 weight transposes in one launch (z selects matrix)
__global__ void transpose_cast4(const float* __restrict__ W0, const float* __restrict__ W1,
                                const float* __restrict__ W2, const float* __restrict__ W3,
                                bf16* __restrict__ O0, bf16* __restrict__ O1,
                                bf16* __restrict__ O2, bf16* __restrict__ O3) {
  const float* in; bf16* out;
  switch (blockIdx.z) {
    case 0: in = W0; out = O0; break;
    case 1: in = W1; out = O1; break;
    case 2: in = W2; out = O2; break;
    default: in = W3; out = O3; break;
  }
  transpose_tile(in, out, DD, DD);
}

// fused: the two 2048x1024 Wc/We transposes in one launch
__global__ void transpose_cast2(const float* __restrict__ W0, const float* __restrict__ W1,
                                bf16* __restrict__ O0, bf16* __restrict__ O1) {
  const float* in = blockIdx.z ? W1 : W0;
  bf16* out = blockIdx.z ? O1 : O0;
  transpose_tile(in, out, NN, DD);
}

// fused cg prep: one read of cg -> cgb (cast, same layout) AND cgT (cast, transposed)
__global__ void cg_prep(const float* __restrict__ in, bf16* __restrict__ outN,
                        bf16* __restrict__ outT) {
  __shared__ float t[32][33];
  int c0 = blockIdx.x * 32, r0 = blockIdx.y * 32;
  int tx = threadIdx.x, ty = threadIdx.y;  // block (32,8)
#pragma unroll
  for (int i = 0; i < 4; i++) {
    float v = in[(size_t)(r0 + ty + i * 8) * NN + c0 + tx];
    t[ty + i * 8][tx] = v;
    outN[(size_t)(r0 + ty + i * 8) * NN + c0 + tx] = __float2bfloat16(v);
  }
  __syncthreads();
#pragma unroll
  for (int i = 0; i < 4; i++)
    outT[(size_t)(c0 + ty + i * 8) * NN + r0 + tx] = __float2bfloat16(t[tx][ty + i * 8]);
}

// ---------------- bf16->bf16 transpose of V into per-head layout ----------------
// Vb [B*N][D] -> Vt [B*H][64][N]  (Vt[bh][d][n] = Vb[b*N+n][h*64+d])
__global__ void transpose_v(const bf16* __restrict__ Vb, bf16* __restrict__ Vt) {
  __shared__ short t[32][33];
  int bh = blockIdx.z; int b = bh >> 4, h = bh & 15;
  int n0 = blockIdx.x * 32, d0 = blockIdx.y * 32;
  int tx = threadIdx.x, ty = threadIdx.y;  // block (32,8)
#pragma unroll
  for (int i = 0; i < 4; i++)
    t[ty + i * 8][tx] = reinterpret_cast<const short*>(Vb)[
        (size_t)(b * NN + n0 + ty + i * 8) * DD + h * 64 + d0 + tx];
  __syncthreads();
#pragma unroll
  for (int i = 0; i < 4; i++)
    reinterpret_cast<short*>(Vt)[(size_t)(bh * 64 + d0 + ty + i * 8) * NN + n0 + tx] =
        t[tx][ty + i * 8];
}

// ---------------- GEMM tile body (compile-time rowadd) ----------------
template <int OUT_BF16, int HAS_ROWADD>
__device__ __forceinline__ void gemm_tile(
    const bf16* __restrict__ A, const bf16* __restrict__ BT, void* __restrict__ Cout,
    const float* __restrict__ bias, const float* __restrict__ rowadd,
    int Nc, int K, float scale, int brow, int bcol, short* As, short* Bs) {
  const int tid = threadIdx.x;
  const int l = tid & 63, w = tid >> 6;
  const int wr = (w >> 1) * 64, wc = (w & 1) * 64;
  const int lr = l & 15, lg = l >> 4;
  const int swz = lr & 7;
  f32x4 acc[4][4] = {};
  for (int k0 = 0; k0 < K; k0 += 64) {
#pragma unroll
    for (int i = 0; i < 4; i++) {
      int c = i * 256 + tid;          // chunk index 0..1023 (16B chunks)
      int row = c >> 3, gch = (c & 7) ^ (row & 7);
      short* lA = As + (size_t)(i * 256 + w * 64) * 8;  // wave-uniform dest
      GLOAD_LDS16(A + (size_t)(brow + row) * K + k0 + gch * 8, lA);
      short* lB = Bs + (size_t)(i * 256 + w * 64) * 8;
      GLOAD_LDS16(BT + (size_t)(bcol + row) * K + k0 + gch * 8, lB);
    }
    __syncthreads();
#pragma unroll
    for (int t = 0; t < 2; t++) {
      bf16x8s a[4], bfr[4];
#pragma unroll
      for (int m = 0; m < 4; m++)
        a[m] = *reinterpret_cast<const bf16x8s*>(
            &As[(wr + m * 16 + lr) * 64 + ((t * 4 + lg) ^ swz) * 8]);
#pragma unroll
      for (int n = 0; n < 4; n++)
        bfr[n] = *reinterpret_cast<const bf16x8s*>(
            &Bs[(wc + n * 16 + lr) * 64 + ((t * 4 + lg) ^ swz) * 8]);
#pragma unroll
      for (int m = 0; m < 4; m++)
#pragma unroll
        for (int n = 0; n < 4; n++)
          acc[m][n] = __builtin_amdgcn_mfma_f32_16x16x32_bf16(a[m], bfr[n], acc[m][n], 0, 0, 0);
    }
    __syncthreads();
  }
#pragma unroll
  for (int m = 0; m < 4; m++) {
#pragma unroll
    for (int n = 0; n < 4; n++) {
      int col = bcol + wc + n * 16 + lr;
      float bv = bias[col];
#pragma unroll
      for (int r = 0; r < 4; r++) {
        int row = brow + wr + m * 16 + lg * 4 + r;
        float v = acc[m][n][r] + bv;
        if (HAS_ROWADD) v += rowadd[(size_t)(row & (NN - 1)) * Nc + col];
        v *= scale;
        if (OUT_BF16)
          reinterpret_cast<bf16*>(Cout)[(size_t)row * Nc + col] = __float2bfloat16(v);
        else
          reinterpret_cast<float*>(Cout)[(size_t)row * Nc + col] = v;
      }
    }
  }
}

// ---------------- bf16 MFMA GEMM, 128x128 tile, BK=64, XCD-swizzled ----------------
template <int OUT_BF16, int HAS_ROWADD>
__global__ __launch_bounds__(256) void gemm_bt(
    const bf16* __restrict__ A, const bf16* __restrict__ BT, void* __restrict__ Cout,
    const float* __restrict__ bias, const float* __restrict__ rowadd,
    int M, int Nc, int K, float scale) {
  __shared__ short As[128 * 64];
  __shared__ short Bs[128 * 64];
  const int nbx = gridDim.x;
  const int nwg = nbx * gridDim.y;
  const int wg = blockIdx.y * nbx + blockIdx.x;
  const int swg = (wg & 7) * (nwg >> 3) + (wg >> 3);
  const int bxi = swg % nbx, byi = swg / nbx;
  gemm_tile<OUT_BF16, HAS_ROWADD>(A, BT, Cout, bias, rowadd, Nc, K, scale,
                                  byi * 128, bxi * 128, As, Bs);
}

// ---------------- dual GEMM: the two 2048x1024x2048 cg GEMMs fill the chip ----------
__global__ __launch_bounds__(256) void gemm_dual(
    const bf16* __restrict__ A0, const bf16* __restrict__ B0, float* __restrict__ C0,
    const float* __restrict__ bias0,
    const bf16* __restrict__ A1, const bf16* __restrict__ B1, float* __restrict__ C1,
    const float* __restrict__ bias1, int Nc, int K) {
  __shared__ short As[128 * 64];
  __shared__ short Bs[128 * 64];
  const int nbx = gridDim.x;
  const int nwg = nbx * gridDim.y;
  const int wg = blockIdx.y * nbx + blockIdx.x;
  const int swg = (wg & 7) * (nwg >> 3) + (wg >> 3);
  const int bxi = swg % nbx, byi = swg / nbx;
  if (blockIdx.z == 0)
    gemm_tile<0, 0>(A0, B0, C0, bias0, nullptr, Nc, K, 1.0f, byi * 128, bxi * 128, As, Bs);
  else
    gemm_tile<0, 0>(A1, B1, C1, bias1, nullptr, Nc, K, 1.0f, byi * 128, bxi * 128, As, Bs);
}

// ---------------- flash attention: 128-row q-tile, 8 waves, swapped-operand QK^T ----
// (R10/R12 configuration — fastest measured: 160.5 us, VGPR 48, occupancy ~45%.)
// grid 1024 linear, XCD chunk with h fastest (8 K/V panels = 4MB L2-fit per XCD).
// Each of 8 waves owns 16 q-rows; one K/V staging+barrier pair feeds 128 q-rows.
// mfma(K,Q): q = lane&15, kv on reg axis -> in-lane softmax, scalar m/l.
// Mask issued early (before prefetch) so its vmcnt drain leaves prefetch in flight.
__global__ __launch_bounds__(512, 4) void attn_k(
    const bf16* __restrict__ Qb, const bf16* __restrict__ Kb, const bf16* __restrict__ Vt,
    const float* __restrict__ mask, bf16* __restrict__ Ob) {
  constexpr int PPAD = 72;
  __shared__ short Ks[64 * 64];
  __shared__ short Vts[64 * 64];
  __shared__ short Ps[8][16 * PPAD];
  const int tid = threadIdx.x;
  // XCD swizzle: x = xcd, i = intra-chunk (128/XCD); h fastest, then q-tile
  const int wg = blockIdx.x;
  const int x = wg & 7, i = wg >> 3;
  const int b = x >> 1;
  const int h = ((x & 1) << 3) | (i & 7);
  const int q0 = ((i >> 3) & 15) * 128;
  const int l = tid & 63, w = tid >> 6;   // 8 waves
  const int lr = l & 15, lg = l >> 4, lk = lg * 8;
  const int swz = lr & 7;

  // Q fragment: lane holds Q-row q = q0 + w*16 + lr  [B-operand of mfma(K,Q)]
  const size_t qoff = (size_t)(b * NN + q0 + w * 16 + lr) * DD + h * 64;
  bf16x8s qf0 = *reinterpret_cast<const bf16x8s*>(Qb + qoff + lk);
  bf16x8s qf1 = *reinterpret_cast<const bf16x8s*>(Qb + qoff + 32 + lk);

  f32x4 acc[4] = {};          // O^T: col q, row d = s4*16 + lg*4 + r
  float mrun = -1e30f, lrun = 0.f;  // per-lane scalars

  const size_t kbase = (size_t)b * NN * DD + h * 64;
  const size_t vbase = (size_t)(b * HH + h) * 64 * NN;
  const float* mptr = mask + (size_t)(q0 + w * 16 + lr) * NN + lg * 4;  // lane's q-row

  // staging: 512 threads cover the 512 16B chunks of each tile (1 K + 1 V chunk each)
  const int r0 = tid >> 3, ch0 = tid & 7;
  const bf16* kg0 = Kb + kbase + (size_t)r0 * DD + ch0 * 8;
  const bf16* vg0 = Vt + vbase + (size_t)r0 * NN + ch0 * 8;
  // LDS dest slot ch0^(row&7) holds global chunk ch0 (read side XORs the same)
  short* kw0 = &Ks[r0 * 64 + (ch0 ^ (r0 & 7)) * 8];
  short* vw0 = &Vts[r0 * 64 + (ch0 ^ (r0 & 7)) * 8];

  uint4 kr0, vr0;
  kr0 = *reinterpret_cast<const uint4*>(kg0);   // prologue: prefetch tile 0
  vr0 = *reinterpret_cast<const uint4*>(vg0);

  for (int jt = 0; jt < NN; jt += 64) {
    __syncthreads();  // prior tile's readers done before overwrite
    *reinterpret_cast<uint4*>(kw0) = kr0;
    *reinterpret_cast<uint4*>(vw0) = vr0;
    // mask loads for CURRENT tile, issued BEFORE the K/V prefetch: the logits'
    // vmcnt wait drains only these 4 (prefetch stays in flight across the tile)
    float4 m0 = *reinterpret_cast<const float4*>(mptr + jt + 0);
    float4 m1 = *reinterpret_cast<const float4*>(mptr + jt + 16);
    float4 m2 = *reinterpret_cast<const float4*>(mptr + jt + 32);
    float4 m3 = *reinterpret_cast<const float4*>(mptr + jt + 48);
    if (jt + 64 < NN) {  // prefetch next tile; loads fly during compute below
      kr0 = *reinterpret_cast<const uint4*>(kg0 + (size_t)(jt + 64) * DD);
      vr0 = *reinterpret_cast<const uint4*>(vg0 + jt + 64);
    }
    __syncthreads();

    // S^T = K Q^T: s[jj][r] = S[kv = jt + jj*16 + lg*4 + r][q]
    f32x4 s[4];
#pragma unroll
    for (int jj = 0; jj < 4; jj++) {
      bf16x8s k0 = *reinterpret_cast<const bf16x8s*>(
          &Ks[(jj * 16 + lr) * 64 + ((0 + lg) ^ swz) * 8]);
      bf16x8s k1 = *reinterpret_cast<const bf16x8s*>(
          &Ks[(jj * 16 + lr) * 64 + ((4 + lg) ^ swz) * 8]);
      f32x4 z = {0.f, 0.f, 0.f, 0.f};
      z = __builtin_amdgcn_mfma_f32_16x16x32_bf16(k0, qf0, z, 0, 0, 0);
      s[jj] = __builtin_amdgcn_mfma_f32_16x16x32_bf16(k1, qf1, z, 0, 0, 0);
    }

    // logits (log2 domain; log2e folded into Q), mask from registers
    float lv[4][4];
    lv[0][0] = s[0][0] * m0.x; lv[0][1] = s[0][1] * m0.y;
    lv[0][2] = s[0][2] * m0.z; lv[0][3] = s[0][3] * m0.w;
    lv[1][0] = s[1][0] * m1.x; lv[1][1] = s[1][1] * m1.y;
    lv[1][2] = s[1][2] * m1.z; lv[1][3] = s[1][3] * m1.w;
    lv[2][0] = s[2][0] * m2.x; lv[2][1] = s[2][1] * m2.y;
    lv[2][2] = s[2][2] * m2.z; lv[2][3] = s[2][3] * m2.w;
    lv[3][0] = s[3][0] * m3.x; lv[3][1] = s[3][1] * m3.y;
    lv[3][2] = s[3][2] * m3.z; lv[3][3] = s[3][3] * m3.w;

    // full row max: 15 in-lane fmax + 2 cross-group shuffles
    float mx0 = fmaxf(fmaxf(lv[0][0], lv[0][1]), fmaxf(lv[0][2], lv[0][3]));
    float mx1 = fmaxf(fmaxf(lv[1][0], lv[1][1]), fmaxf(lv[1][2], lv[1][3]));
    float mx2 = fmaxf(fmaxf(lv[2][0], lv[2][1]), fmaxf(lv[2][2], lv[2][3]));
    float mx3 = fmaxf(fmaxf(lv[3][0], lv[3][1]), fmaxf(lv[3][2], lv[3][3]));
    float mx = fmaxf(fmaxf(mx0, mx1), fmaxf(mx2, mx3));
    mx = fmaxf(mx, __shfl_xor(mx, 16, 64));
    mx = fmaxf(mx, __shfl_xor(mx, 32, 64));

    // defer-max: rescale only if this row grew by > 11 (log2 domain)
    if (__any(mx > mrun + 11.0f)) {
      float mnew = fmaxf(mrun, mx);
      float sc = __builtin_amdgcn_exp2f(mrun - mnew);
      mrun = mnew;
      lrun *= sc;
#pragma unroll
      for (int s4 = 0; s4 < 4; s4++)
#pragma unroll
        for (int r = 0; r < 4; r++) acc[s4][r] *= sc;
    }

    // P = exp2(lv - m): 16 values, pack 4 bf16 per jj -> one ds_write_b64 each
    short* Pw = &Ps[w][0];
    float rs = 0.f;
#pragma unroll
    for (int jj = 0; jj < 4; jj++) {
      float p0 = __builtin_amdgcn_exp2f(lv[jj][0] - mrun);
      float p1 = __builtin_amdgcn_exp2f(lv[jj][1] - mrun);
      float p2 = __builtin_amdgcn_exp2f(lv[jj][2] - mrun);
      float p3 = __builtin_amdgcn_exp2f(lv[jj][3] - mrun);
      rs += (p0 + p1) + (p2 + p3);
      ushort4 pk;
      bf16 b0 = __float2bfloat16(p0); pk.x = *reinterpret_cast<unsigned short*>(&b0);
      bf16 b1 = __float2bfloat16(p1); pk.y = *reinterpret_cast<unsigned short*>(&b1);
      bf16 b2 = __float2bfloat16(p2); pk.z = *reinterpret_cast<unsigned short*>(&b2);
      bf16 b3 = __float2bfloat16(p3); pk.w = *reinterpret_cast<unsigned short*>(&b3);
      *reinterpret_cast<ushort4*>(&Pw[lr * PPAD + jj * 16 + lg * 4]) = pk;
    }
    rs += __shfl_xor(rs, 16, 64);
    rs += __shfl_xor(rs, 32, 64);
    lrun += rs;

    // wave-private P: drain DS writes, fence the scheduler, no block barrier
    asm volatile("s_waitcnt lgkmcnt(0)" ::: "memory");
    __builtin_amdgcn_sched_barrier(0);

    // O^T += V^T P^T : A = V^T rows d, B = P rows q
    bf16x8s pb0 = *reinterpret_cast<const bf16x8s*>(&Pw[lr * PPAD + lk]);
    bf16x8s pb1 = *reinterpret_cast<const bf16x8s*>(&Pw[lr * PPAD + 32 + lk]);
#pragma unroll
    for (int s4 = 0; s4 < 4; s4++) {
      bf16x8s v0 = *reinterpret_cast<const bf16x8s*>(
          &Vts[(s4 * 16 + lr) * 64 + ((0 + lg) ^ swz) * 8]);
      bf16x8s v1 = *reinterpret_cast<const bf16x8s*>(
          &Vts[(s4 * 16 + lr) * 64 + ((4 + lg) ^ swz) * 8]);
      acc[s4] = __builtin_amdgcn_mfma_f32_16x16x32_bf16(v0, pb0, acc[s4], 0, 0, 0);
      acc[s4] = __builtin_amdgcn_mfma_f32_16x16x32_bf16(v1, pb1, acc[s4], 0, 0, 0);
    }
  }

  // epilogue: normalize (1 rcp/lane), pack 4 consecutive d per s4 -> 8B stores
  float rl = __builtin_amdgcn_rcpf(lrun);
  const size_t orow = (size_t)(b * NN + q0 + w * 16 + lr) * DD + h * 64;
#pragma unroll
  for (int s4 = 0; s4 < 4; s4++) {
    ushort4 o;
    bf16 b0 = __float2bfloat16(acc[s4][0] * rl); o.x = *reinterpret_cast<unsigned short*>(&b0);
    bf16 b1 = __float2bfloat16(acc[s4][1] * rl); o.y = *reinterpret_cast<unsigned short*>(&b1);
    bf16 b2 = __float2bfloat16(acc[s4][2] * rl); o.z = *reinterpret_cast<unsigned short*>(&b2);
    bf16 b3 = __float2bfloat16(acc[s4][3] * rl); o.w = *reinterpret_cast<unsigned short*>(&b3);
    *reinterpret_cast<ushort4*>(reinterpret_cast<unsigned short*>(Ob) + orow + s4 * 16 + lg * 4) = o;
  }
}

// ---------------- orchestration ----------------
extern "C" void kernel_launch(void* const* d_in, const int* in_sizes, int n_in,
                              void* d_out, int out_size, void* d_ws, size_t ws_size,
                              hipStream_t stream) {
  (void)in_sizes; (void)n_in; (void)out_size; (void)ws_size;
  const float* x    = (const float*)d_in[0];
  const float* cg   = (const float*)d_in[1];
  const float* mask = (const float*)d_in[2];
  const float* Wq   = (const float*)d_in[3];
  const float* bq   = (const float*)d_in[4];
  const float* Wk   = (const float*)d_in[5];
  const float* bk   = (const float*)d_in[6];
  const float* Wc   = (const float*)d_in[7];
  const float* bc   = (const float*)d_in[8];
  const float* We   = (const float*)d_in[9];
  const float* be   = (const float*)d_in[10];
  const float* Wv   = (const float*)d_in[11];
  const float* bv   = (const float*)d_in[12];
  const float* Wo   = (const float*)d_in[13];
  const float* bo   = (const float*)d_in[14];

  auto MB = [](size_t m) { return m << 20; };
  char* ws = (char*)d_ws;
  bf16* xb   = (bf16*)(ws + MB(0));    // 16 MB
  bf16* WqT  = (bf16*)(ws + MB(16));   // 2 MB each
  bf16* WkT  = (bf16*)(ws + MB(18));
  bf16* WvT  = (bf16*)(ws + MB(20));
  bf16* WoT  = (bf16*)(ws + MB(22));
  float* cq  = (float*)(ws + MB(24));  // 8 MB f32 (dead after Q GEMM)
  float* ck  = (float*)(ws + MB(32));  // 8 MB f32 (dead after K GEMM)
  bf16* Qb   = (bf16*)(ws + MB(40));   // 16 MB
  bf16* Kb   = (bf16*)(ws + MB(56));   // 16 MB
  bf16* Vb   = (bf16*)(ws + MB(72));   // 16 MB (dead after transpose_v)
  bf16* Vt   = (bf16*)(ws + MB(88));   // 16 MB -> peak 104 MB
  bf16* Ob   = (bf16*)(ws + MB(72));   // overlays Vb (dead)
  // overlays, dead after cq/ck GEMMs (before Qb/Kb are written):
  bf16* WcT  = (bf16*)(ws + MB(40));   // 4 MB
  bf16* WeT  = (bf16*)(ws + MB(44));   // 4 MB
  bf16* cgb  = (bf16*)(ws + MB(48));   // 8 MB
  bf16* cgT  = (bf16*)(ws + MB(56));   // 8 MB

  cast_f32_bf16<<<dim3(BB * NN * DD / 4 / 256), 256, 0, stream>>>(x, xb, BB * NN * DD);
  dim3 tb(32, 8);
  cg_prep<<<dim3(NN / 32, NN / 32), tb, 0, stream>>>(cg, cgb, cgT);
  transpose_cast4<<<dim3(DD / 32, DD / 32, 4), tb, 0, stream>>>(
      Wq, Wk, Wv, Wo, WqT, WkT, WvT, WoT);
  transpose_cast2<<<dim3(DD / 32, NN / 32, 2), tb, 0, stream>>>(Wc, We, WcT, WeT);

  // cq = cg@Wc + bc AND ck = cg^T@We + be in one full-chip launch (256 blocks)
  gemm_dual<<<dim3(DD / 128, NN / 128, 2), 256, 0, stream>>>(
      cgb, WcT, cq, bc, cgT, WeT, ck, be, DD, NN);
  // Q = (0.125*log2e)*(x@Wq + bq + cq[row]) ; K = x@Wk + bk + ck[row] ; V = x@Wv + bv
  gemm_bt<1, 1><<<dim3(DD / 128, BB * NN / 128), 256, 0, stream>>>(
      xb, WqT, Qb, bq, cq, BB * NN, DD, DD, 0.125f * 1.4426950408889634f);
  gemm_bt<1, 1><<<dim3(DD / 128, BB * NN / 128), 256, 0, stream>>>(
      xb, WkT, Kb, bk, ck, BB * NN, DD, DD, 1.0f);
  gemm_bt<1, 0><<<dim3(DD / 128, BB * NN / 128), 256, 0, stream>>>(
      xb, WvT, Vb, bv, nullptr, BB * NN, DD, DD, 1.0f);

  transpose_v<<<dim3(NN / 32, 2, BB * HH), tb, 0, stream>>>(Vb, Vt);

  attn_k<<<dim3(NN / 128 * HH * BB), 512, 0, stream>>>(Qb, Kb, Vt, mask, Ob);

  // out = attn@Wo + bo  (f32 out)
  gemm_bt<0, 0><<<dim3(DD / 128, BB * NN / 128), 256, 0, stream>>>(
      Ob, WoT, (float*)d_out, bo, nullptr, BB * NN, DD, DD, 1.0f);
}

// Round 16
// 305.863 us; speedup vs baseline: 1.1644x; 1.0178x over previous
//
#include <hip/hip_runtime.h>
#include <hip/hip_bf16.h>

#define BB 4
#define NN 2048
#define DD 1024
#define HH 16

using bf16 = __hip_bfloat16;
typedef __attribute__((ext_vector_type(8))) short bf16x8s;
typedef __attribute__((ext_vector_type(4))) float f32x4;

#define GLOAD_LDS16(gp, lp)                                                   \
  __builtin_amdgcn_global_load_lds(                                           \
      (const __attribute__((address_space(1))) void*)(gp),                    \
      (__attribute__((address_space(3))) void*)(lp), 16, 0, 0)

// ---------------- cast f32 -> bf16 (vectorized x4) ----------------
__global__ void cast_f32_bf16(const float* __restrict__ in, bf16* __restrict__ out, int n) {
  int i = (blockIdx.x * blockDim.x + threadIdx.x) * 4;
  if (i >= n) return;
  float4 v = *reinterpret_cast<const float4*>(in + i);
  ushort4 o;
  bf16 t0 = __float2bfloat16(v.x); o.x = *reinterpret_cast<unsigned short*>(&t0);
  bf16 t1 = __float2bfloat16(v.y); o.y = *reinterpret_cast<unsigned short*>(&t1);
  bf16 t2 = __float2bfloat16(v.z); o.z = *reinterpret_cast<unsigned short*>(&t2);
  bf16 t3 = __float2bfloat16(v.w); o.w = *reinterpret_cast<unsigned short*>(&t3);
  *reinterpret_cast<ushort4*>(out + i) = o;
}

// ---------------- transpose + cast: in[R,C] f32 -> out[C,R] bf16 ----------------
__device__ __forceinline__ void transpose_tile(const float* __restrict__ in,
                                               bf16* __restrict__ out, int R, int C) {
  __shared__ float t[32][33];
  int c0 = blockIdx.x * 32, r0 = blockIdx.y * 32;
  int tx = threadIdx.x, ty = threadIdx.y;  // block (32,8)
#pragma unroll
  for (int i = 0; i < 4; i++)
    t[ty + i * 8][tx] = in[(size_t)(r0 + ty + i * 8) * C + c0 + tx];
  __syncthreads();
#pragma unroll
  for (int i = 0; i < 4; i++)
    out[(size_t)(c0 + ty + i * 8) * R + r0 + tx] = __float2bfloat16(t[tx][ty + i * 8]);
}

// fused: the four 1024x1024 weight transposes in one launch (z selects matrix)
__global__ void transpose_cast4(const float* __restrict__ W0, const float* __restrict__ W1,
                                const float* __restrict__ W2, const float* __restrict__ W3,
                                bf16* __restrict__ O0, bf16* __restrict__ O1,
                                bf16* __restrict__ O2, bf16* __restrict__ O3) {
  const float* in; bf16* out;
  switch (blockIdx.z) {
    case 0: in = W0; out = O0; break;
    case 1: in = W1; out = O1; break;
    case 2: in = W2; out = O2; break;
    default: in = W3; out = O3; break;
  }
  transpose_tile(in, out, DD, DD);
}

// fused: the two 2048x1024 Wc/We transposes in one launch
__global__ void transpose_cast2(const float* __restrict__ W0, const float* __restrict__ W1,
                                bf16* __restrict__ O0, bf16* __restrict__ O1) {
  const float* in = blockIdx.z ? W1 : W0;
  bf16* out = blockIdx.z ? O1 : O0;
  transpose_tile(in, out, NN, DD);
}

// fused cg prep: one read of cg -> cgb (cast, same layout) AND cgT (cast, transposed)
__global__ void cg_prep(const float* __restrict__ in, bf16* __restrict__ outN,
                        bf16* __restrict__ outT) {
  __shared__ float t[32][33];
  int c0 = blockIdx.x * 32, r0 = blockIdx.y * 32;
  int tx = threadIdx.x, ty = threadIdx.y;  // block (32,8)
#pragma unroll
  for (int i = 0; i < 4; i++) {
    float v = in[(size_t)(r0 + ty + i * 8) * NN + c0 + tx];
    t[ty + i * 8][tx] = v;
    outN[(size_t)(r0 + ty + i * 8) * NN + c0 + tx] = __float2bfloat16(v);
  }
  __syncthreads();
#pragma unroll
  for (int i = 0; i < 4; i++)
    outT[(size_t)(c0 + ty + i * 8) * NN + r0 + tx] = __float2bfloat16(t[tx][ty + i * 8]);
}

// ---------------- GEMM tile body ----------------
// OUT_MODE: 0 = f32 natural layout, 1 = bf16 natural layout,
//           2 = bf16 per-head TRANSPOSED (Vt[((b*HH+h)*64+d)*NN + n]) — fuses the
//               old transpose_v pass into the V-GEMM epilogue. Each lane's 4
//               consecutive rows (n) pack to one ushort4; lg-groups tile 32B runs.
template <int OUT_MODE, int HAS_ROWADD>
__device__ __forceinline__ void gemm_tile(
    const bf16* __restrict__ A, const bf16* __restrict__ BT, void* __restrict__ Cout,
    const float* __restrict__ bias, const float* __restrict__ rowadd,
    int Nc, int K, float scale, int brow, int bcol, short* As, short* Bs) {
  const int tid = threadIdx.x;
  const int l = tid & 63, w = tid >> 6;
  const int wr = (w >> 1) * 64, wc = (w & 1) * 64;
  const int lr = l & 15, lg = l >> 4;
  const int swz = lr & 7;
  f32x4 acc[4][4] = {};
  for (int k0 = 0; k0 < K; k0 += 64) {
#pragma unroll
    for (int i = 0; i < 4; i++) {
      int c = i * 256 + tid;          // chunk index 0..1023 (16B chunks)
      int row = c >> 3, gch = (c & 7) ^ (row & 7);
      short* lA = As + (size_t)(i * 256 + w * 64) * 8;  // wave-uniform dest
      GLOAD_LDS16(A + (size_t)(brow + row) * K + k0 + gch * 8, lA);
      short* lB = Bs + (size_t)(i * 256 + w * 64) * 8;
      GLOAD_LDS16(BT + (size_t)(bcol + row) * K + k0 + gch * 8, lB);
    }
    __syncthreads();
#pragma unroll
    for (int t = 0; t < 2; t++) {
      bf16x8s a[4], bfr[4];
#pragma unroll
      for (int m = 0; m < 4; m++)
        a[m] = *reinterpret_cast<const bf16x8s*>(
            &As[(wr + m * 16 + lr) * 64 + ((t * 4 + lg) ^ swz) * 8]);
#pragma unroll
      for (int n = 0; n < 4; n++)
        bfr[n] = *reinterpret_cast<const bf16x8s*>(
            &Bs[(wc + n * 16 + lr) * 64 + ((t * 4 + lg) ^ swz) * 8]);
#pragma unroll
      for (int m = 0; m < 4; m++)
#pragma unroll
        for (int n = 0; n < 4; n++)
          acc[m][n] = __builtin_amdgcn_mfma_f32_16x16x32_bf16(a[m], bfr[n], acc[m][n], 0, 0, 0);
    }
    __syncthreads();
  }
#pragma unroll
  for (int m = 0; m < 4; m++) {
#pragma unroll
    for (int n = 0; n < 4; n++) {
      int col = bcol + wc + n * 16 + lr;
      float bv = bias[col];
      if (OUT_MODE == 2) {
        // transposed per-head write: 4 consecutive n-rows -> one 8B store
        int rowb = brow + wr + m * 16 + lg * 4;
        int b_ = rowb >> 11, n_ = rowb & (NN - 1);
        int h_ = col >> 6, d_ = col & 63;
        ushort4 o;
        float v0 = (acc[m][n][0] + bv) * scale;
        float v1 = (acc[m][n][1] + bv) * scale;
        float v2 = (acc[m][n][2] + bv) * scale;
        float v3 = (acc[m][n][3] + bv) * scale;
        bf16 c0 = __float2bfloat16(v0); o.x = *reinterpret_cast<unsigned short*>(&c0);
        bf16 c1 = __float2bfloat16(v1); o.y = *reinterpret_cast<unsigned short*>(&c1);
        bf16 c2 = __float2bfloat16(v2); o.z = *reinterpret_cast<unsigned short*>(&c2);
        bf16 c3 = __float2bfloat16(v3); o.w = *reinterpret_cast<unsigned short*>(&c3);
        *reinterpret_cast<ushort4*>(
            reinterpret_cast<unsigned short*>(Cout) +
            ((size_t)(b_ * HH + h_) * 64 + d_) * NN + n_) = o;
      } else {
#pragma unroll
        for (int r = 0; r < 4; r++) {
          int row = brow + wr + m * 16 + lg * 4 + r;
          float v = acc[m][n][r] + bv;
          if (HAS_ROWADD) v += rowadd[(size_t)(row & (NN - 1)) * Nc + col];
          v *= scale;
          if (OUT_MODE == 1)
            reinterpret_cast<bf16*>(Cout)[(size_t)row * Nc + col] = __float2bfloat16(v);
          else
            reinterpret_cast<float*>(Cout)[(size_t)row * Nc + col] = v;
        }
      }
    }
  }
}

// ---------------- bf16 MFMA GEMM, 128x128 tile, BK=64, XCD-swizzled ----------------
template <int OUT_MODE, int HAS_ROWADD>
__global__ __launch_bounds__(256) void gemm_bt(
    const bf16* __restrict__ A, const bf16* __restrict__ BT, void* __restrict__ Cout,
    const float* __restrict__ bias, const float* __restrict__ rowadd,
    int M, int Nc, int K, float scale) {
  __shared__ short As[128 * 64];
  __shared__ short Bs[128 * 64];
  const int nbx = gridDim.x;
  const int nwg = nbx * gridDim.y;
  const int wg = blockIdx.y * nbx + blockIdx.x;
  const int swg = (wg & 7) * (nwg >> 3) + (wg >> 3);
  const int bxi = swg % nbx, byi = swg / nbx;
  gemm_tile<OUT_MODE, HAS_ROWADD>(A, BT, Cout, bias, rowadd, Nc, K, scale,
                                  byi * 128, bxi * 128, As, Bs);
}

// ---------------- dual GEMM: the two 2048x1024x2048 cg GEMMs fill the chip ----------
__global__ __launch_bounds__(256) void gemm_dual(
    const bf16* __restrict__ A0, const bf16* __restrict__ B0, float* __restrict__ C0,
    const float* __restrict__ bias0,
    const bf16* __restrict__ A1, const bf16* __restrict__ B1, float* __restrict__ C1,
    const float* __restrict__ bias1, int Nc, int K) {
  __shared__ short As[128 * 64];
  __shared__ short Bs[128 * 64];
  const int nbx = gridDim.x;
  const int nwg = nbx * gridDim.y;
  const int wg = blockIdx.y * nbx + blockIdx.x;
  const int swg = (wg & 7) * (nwg >> 3) + (wg >> 3);
  const int bxi = swg % nbx, byi = swg / nbx;
  if (blockIdx.z == 0)
    gemm_tile<0, 0>(A0, B0, C0, bias0, nullptr, Nc, K, 1.0f, byi * 128, bxi * 128, As, Bs);
  else
    gemm_tile<0, 0>(A1, B1, C1, bias1, nullptr, Nc, K, 1.0f, byi * 128, bxi * 128, As, Bs);
}

// ---------------- flash attention: 128-row q-tile, 8 waves, swapped-operand QK^T ----
// (R10/R12 configuration — fastest measured: 160.5 us, VGPR 48, occupancy ~45%.)
// grid 1024 linear, XCD chunk with h fastest (8 K/V panels = 4MB L2-fit per XCD).
// Each of 8 waves owns 16 q-rows; one K/V staging+barrier pair feeds 128 q-rows.
// mfma(K,Q): q = lane&15, kv on reg axis -> in-lane softmax, scalar m/l.
// Mask issued early (before prefetch) so its vmcnt drain leaves prefetch in flight.
__global__ __launch_bounds__(512, 4) void attn_k(
    const bf16* __restrict__ Qb, const bf16* __restrict__ Kb, const bf16* __restrict__ Vt,
    const float* __restrict__ mask, bf16* __restrict__ Ob) {
  constexpr int PPAD = 72;
  __shared__ short Ks[64 * 64];
  __shared__ short Vts[64 * 64];
  __shared__ short Ps[8][16 * PPAD];
  const int tid = threadIdx.x;
  // XCD swizzle: x = xcd, i = intra-chunk (128/XCD); h fastest, then q-tile
  const int wg = blockIdx.x;
  const int x = wg & 7, i = wg >> 3;
  const int b = x >> 1;
  const int h = ((x & 1) << 3) | (i & 7);
  const int q0 = ((i >> 3) & 15) * 128;
  const int l = tid & 63, w = tid >> 6;   // 8 waves
  const int lr = l & 15, lg = l >> 4, lk = lg * 8;
  const int swz = lr & 7;

  // Q fragment: lane holds Q-row q = q0 + w*16 + lr  [B-operand of mfma(K,Q)]
  const size_t qoff = (size_t)(b * NN + q0 + w * 16 + lr) * DD + h * 64;
  bf16x8s qf0 = *reinterpret_cast<const bf16x8s*>(Qb + qoff + lk);
  bf16x8s qf1 = *reinterpret_cast<const bf16x8s*>(Qb + qoff + 32 + lk);

  f32x4 acc[4] = {};          // O^T: col q, row d = s4*16 + lg*4 + r
  float mrun = -1e30f, lrun = 0.f;  // per-lane scalars

  const size_t kbase = (size_t)b * NN * DD + h * 64;
  const size_t vbase = (size_t)(b * HH + h) * 64 * NN;
  const float* mptr = mask + (size_t)(q0 + w * 16 + lr) * NN + lg * 4;  // lane's q-row

  // staging: 512 threads cover the 512 16B chunks of each tile (1 K + 1 V chunk each)
  const int r0 = tid >> 3, ch0 = tid & 7;
  const bf16* kg0 = Kb + kbase + (size_t)r0 * DD + ch0 * 8;
  const bf16* vg0 = Vt + vbase + (size_t)r0 * NN + ch0 * 8;
  // LDS dest slot ch0^(row&7) holds global chunk ch0 (read side XORs the same)
  short* kw0 = &Ks[r0 * 64 + (ch0 ^ (r0 & 7)) * 8];
  short* vw0 = &Vts[r0 * 64 + (ch0 ^ (r0 & 7)) * 8];

  uint4 kr0, vr0;
  kr0 = *reinterpret_cast<const uint4*>(kg0);   // prologue: prefetch tile 0
  vr0 = *reinterpret_cast<const uint4*>(vg0);

  for (int jt = 0; jt < NN; jt += 64) {
    __syncthreads();  // prior tile's readers done before overwrite
    *reinterpret_cast<uint4*>(kw0) = kr0;
    *reinterpret_cast<uint4*>(vw0) = vr0;
    // mask loads for CURRENT tile, issued BEFORE the K/V prefetch: the logits'
    // vmcnt wait drains only these 4 (prefetch stays in flight across the tile)
    float4 m0 = *reinterpret_cast<const float4*>(mptr + jt + 0);
    float4 m1 = *reinterpret_cast<const float4*>(mptr + jt + 16);
    float4 m2 = *reinterpret_cast<const float4*>(mptr + jt + 32);
    float4 m3 = *reinterpret_cast<const float4*>(mptr + jt + 48);
    if (jt + 64 < NN) {  // prefetch next tile; loads fly during compute below
      kr0 = *reinterpret_cast<const uint4*>(kg0 + (size_t)(jt + 64) * DD);
      vr0 = *reinterpret_cast<const uint4*>(vg0 + jt + 64);
    }
    __syncthreads();

    // S^T = K Q^T: s[jj][r] = S[kv = jt + jj*16 + lg*4 + r][q]
    f32x4 s[4];
#pragma unroll
    for (int jj = 0; jj < 4; jj++) {
      bf16x8s k0 = *reinterpret_cast<const bf16x8s*>(
          &Ks[(jj * 16 + lr) * 64 + ((0 + lg) ^ swz) * 8]);
      bf16x8s k1 = *reinterpret_cast<const bf16x8s*>(
          &Ks[(jj * 16 + lr) * 64 + ((4 + lg) ^ swz) * 8]);
      f32x4 z = {0.f, 0.f, 0.f, 0.f};
      z = __builtin_amdgcn_mfma_f32_16x16x32_bf16(k0, qf0, z, 0, 0, 0);
      s[jj] = __builtin_amdgcn_mfma_f32_16x16x32_bf16(k1, qf1, z, 0, 0, 0);
    }

    // logits (log2 domain; log2e folded into Q), mask from registers
    float lv[4][4];
    lv[0][0] = s[0][0] * m0.x; lv[0][1] = s[0][1] * m0.y;
    lv[0][2] = s[0][2] * m0.z; lv[0][3] = s[0][3] * m0.w;
    lv[1][0] = s[1][0] * m1.x; lv[1][1] = s[1][1] * m1.y;
    lv[1][2] = s[1][2] * m1.z; lv[1][3] = s[1][3] * m1.w;
    lv[2][0] = s[2][0] * m2.x; lv[2][1] = s[2][1] * m2.y;
    lv[2][2] = s[2][2] * m2.z; lv[2][3] = s[2][3] * m2.w;
    lv[3][0] = s[3][0] * m3.x; lv[3][1] = s[3][1] * m3.y;
    lv[3][2] = s[3][2] * m3.z; lv[3][3] = s[3][3] * m3.w;

    // full row max: 15 in-lane fmax + 2 cross-group shuffles
    float mx0 = fmaxf(fmaxf(lv[0][0], lv[0][1]), fmaxf(lv[0][2], lv[0][3]));
    float mx1 = fmaxf(fmaxf(lv[1][0], lv[1][1]), fmaxf(lv[1][2], lv[1][3]));
    float mx2 = fmaxf(fmaxf(lv[2][0], lv[2][1]), fmaxf(lv[2][2], lv[2][3]));
    float mx3 = fmaxf(fmaxf(lv[3][0], lv[3][1]), fmaxf(lv[3][2], lv[3][3]));
    float mx = fmaxf(fmaxf(mx0, mx1), fmaxf(mx2, mx3));
    mx = fmaxf(mx, __shfl_xor(mx, 16, 64));
    mx = fmaxf(mx, __shfl_xor(mx, 32, 64));

    // defer-max: rescale only if this row grew by > 11 (log2 domain)
    if (__any(mx > mrun + 11.0f)) {
      float mnew = fmaxf(mrun, mx);
      float sc = __builtin_amdgcn_exp2f(mrun - mnew);
      mrun = mnew;
      lrun *= sc;
#pragma unroll
      for (int s4 = 0; s4 < 4; s4++)
#pragma unroll
        for (int r = 0; r < 4; r++) acc[s4][r] *= sc;
    }

    // P = exp2(lv - m): 16 values, pack 4 bf16 per jj -> one ds_write_b64 each
    short* Pw = &Ps[w][0];
    float rs = 0.f;
#pragma unroll
    for (int jj = 0; jj < 4; jj++) {
      float p0 = __builtin_amdgcn_exp2f(lv[jj][0] - mrun);
      float p1 = __builtin_amdgcn_exp2f(lv[jj][1] - mrun);
      float p2 = __builtin_amdgcn_exp2f(lv[jj][2] - mrun);
      float p3 = __builtin_amdgcn_exp2f(lv[jj][3] - mrun);
      rs += (p0 + p1) + (p2 + p3);
      ushort4 pk;
      bf16 b0 = __float2bfloat16(p0); pk.x = *reinterpret_cast<unsigned short*>(&b0);
      bf16 b1 = __float2bfloat16(p1); pk.y = *reinterpret_cast<unsigned short*>(&b1);
      bf16 b2 = __float2bfloat16(p2); pk.z = *reinterpret_cast<unsigned short*>(&b2);
      bf16 b3 = __float2bfloat16(p3); pk.w = *reinterpret_cast<unsigned short*>(&b3);
      *reinterpret_cast<ushort4*>(&Pw[lr * PPAD + jj * 16 + lg * 4]) = pk;
    }
    rs += __shfl_xor(rs, 16, 64);
    rs += __shfl_xor(rs, 32, 64);
    lrun += rs;

    // wave-private P: drain DS writes, fence the scheduler, no block barrier
    asm volatile("s_waitcnt lgkmcnt(0)" ::: "memory");
    __builtin_amdgcn_sched_barrier(0);

    // O^T += V^T P^T : A = V^T rows d, B = P rows q
    bf16x8s pb0 = *reinterpret_cast<const bf16x8s*>(&Pw[lr * PPAD + lk]);
    bf16x8s pb1 = *reinterpret_cast<const bf16x8s*>(&Pw[lr * PPAD + 32 + lk]);
#pragma unroll
    for (int s4 = 0; s4 < 4; s4++) {
      bf16x8s v0 = *reinterpret_cast<const bf16x8s*>(
          &Vts[(s4 * 16 + lr) * 64 + ((0 + lg) ^ swz) * 8]);
      bf16x8s v1 = *reinterpret_cast<const bf16x8s*>(
          &Vts[(s4 * 16 + lr) * 64 + ((4 + lg) ^ swz) * 8]);
      acc[s4] = __builtin_amdgcn_mfma_f32_16x16x32_bf16(v0, pb0, acc[s4], 0, 0, 0);
      acc[s4] = __builtin_amdgcn_mfma_f32_16x16x32_bf16(v1, pb1, acc[s4], 0, 0, 0);
    }
  }

  // epilogue: normalize (1 rcp/lane), pack 4 consecutive d per s4 -> 8B stores
  float rl = __builtin_amdgcn_rcpf(lrun);
  const size_t orow = (size_t)(b * NN + q0 + w * 16 + lr) * DD + h * 64;
#pragma unroll
  for (int s4 = 0; s4 < 4; s4++) {
    ushort4 o;
    bf16 b0 = __float2bfloat16(acc[s4][0] * rl); o.x = *reinterpret_cast<unsigned short*>(&b0);
    bf16 b1 = __float2bfloat16(acc[s4][1] * rl); o.y = *reinterpret_cast<unsigned short*>(&b1);
    bf16 b2 = __float2bfloat16(acc[s4][2] * rl); o.z = *reinterpret_cast<unsigned short*>(&b2);
    bf16 b3 = __float2bfloat16(acc[s4][3] * rl); o.w = *reinterpret_cast<unsigned short*>(&b3);
    *reinterpret_cast<ushort4*>(reinterpret_cast<unsigned short*>(Ob) + orow + s4 * 16 + lg * 4) = o;
  }
}

// ---------------- orchestration ----------------
extern "C" void kernel_launch(void* const* d_in, const int* in_sizes, int n_in,
                              void* d_out, int out_size, void* d_ws, size_t ws_size,
                              hipStream_t stream) {
  (void)in_sizes; (void)n_in; (void)out_size; (void)ws_size;
  const float* x    = (const float*)d_in[0];
  const float* cg   = (const float*)d_in[1];
  const float* mask = (const float*)d_in[2];
  const float* Wq   = (const float*)d_in[3];
  const float* bq   = (const float*)d_in[4];
  const float* Wk   = (const float*)d_in[5];
  const float* bk   = (const float*)d_in[6];
  const float* Wc   = (const float*)d_in[7];
  const float* bc   = (const float*)d_in[8];
  const float* We   = (const float*)d_in[9];
  const float* be   = (const float*)d_in[10];
  const float* Wv   = (const float*)d_in[11];
  const float* bv   = (const float*)d_in[12];
  const float* Wo   = (const float*)d_in[13];
  const float* bo   = (const float*)d_in[14];

  auto MB = [](size_t m) { return m << 20; };
  char* ws = (char*)d_ws;
  bf16* xb   = (bf16*)(ws + MB(0));    // 16 MB
  bf16* WqT  = (bf16*)(ws + MB(16));   // 2 MB each
  bf16* WkT  = (bf16*)(ws + MB(18));
  bf16* WvT  = (bf16*)(ws + MB(20));
  bf16* WoT  = (bf16*)(ws + MB(22));
  float* cq  = (float*)(ws + MB(24));  // 8 MB f32 (dead after Q GEMM)
  float* ck  = (float*)(ws + MB(32));  // 8 MB f32 (dead after K GEMM)
  bf16* Qb   = (bf16*)(ws + MB(40));   // 16 MB
  bf16* Kb   = (bf16*)(ws + MB(56));   // 16 MB
  bf16* Ob   = (bf16*)(ws + MB(72));   // 16 MB
  bf16* Vt   = (bf16*)(ws + MB(88));   // 16 MB (written directly by V GEMM)
  // overlays, dead after cq/ck GEMMs (before Qb/Kb are written):
  bf16* WcT  = (bf16*)(ws + MB(40));   // 4 MB
  bf16* WeT  = (bf16*)(ws + MB(44));   // 4 MB
  bf16* cgb  = (bf16*)(ws + MB(48));   // 8 MB
  bf16* cgT  = (bf16*)(ws + MB(56));   // 8 MB

  cast_f32_bf16<<<dim3(BB * NN * DD / 4 / 256), 256, 0, stream>>>(x, xb, BB * NN * DD);
  dim3 tb(32, 8);
  cg_prep<<<dim3(NN / 32, NN / 32), tb, 0, stream>>>(cg, cgb, cgT);
  transpose_cast4<<<dim3(DD / 32, DD / 32, 4), tb, 0, stream>>>(
      Wq, Wk, Wv, Wo, WqT, WkT, WvT, WoT);
  transpose_cast2<<<dim3(DD / 32, NN / 32, 2), tb, 0, stream>>>(Wc, We, WcT, WeT);

  // cq = cg@Wc + bc AND ck = cg^T@We + be in one full-chip launch (256 blocks)
  gemm_dual<<<dim3(DD / 128, NN / 128, 2), 256, 0, stream>>>(
      cgb, WcT, cq, bc, cgT, WeT, ck, be, DD, NN);
  // Q = (0.125*log2e)*(x@Wq + bq + cq[row]) ; K = x@Wk + bk + ck[row]
  gemm_bt<1, 1><<<dim3(DD / 128, BB * NN / 128), 256, 0, stream>>>(
      xb, WqT, Qb, bq, cq, BB * NN, DD, DD, 0.125f * 1.4426950408889634f);
  gemm_bt<1, 1><<<dim3(DD / 128, BB * NN / 128), 256, 0, stream>>>(
      xb, WkT, Kb, bk, ck, BB * NN, DD, DD, 1.0f);
  // V = x@Wv + bv written DIRECTLY in per-head transposed Vt layout (mode 2):
  // fuses the old transpose_v pass (16MB r + 16MB w + launch) into the epilogue.
  gemm_bt<2, 0><<<dim3(DD / 128, BB * NN / 128), 256, 0, stream>>>(
      xb, WvT, Vt, bv, nullptr, BB * NN, DD, DD, 1.0f);

  attn_k<<<dim3(NN / 128 * HH * BB), 512, 0, stream>>>(Qb, Kb, Vt, mask, Ob);

  // out = attn@Wo + bo  (f32 out)
  gemm_bt<0, 0><<<dim3(DD / 128, BB * NN / 128), 256, 0, stream>>>(
      Ob, WoT, (float*)d_out, bo, nullptr, BB * NN, DD, DD, 1.0f);
}